// Round 6
// baseline (176.477 us; speedup 1.0000x reference)
//
#include <hip/hip_runtime.h>

// Backflow: out[b] = sum_d det(g[b,d]) * bf[d]
//   g[b,d][i][j] = sum_h h2[b,h]*Wg[h,d,sel[b,i],j] + bg[d,sel[b,i],j]
// B=8192, O=64, E=16, D=16, H=4.
//
// One wave per sample; 4 lanes per det; lane l owns rows l, l+4, l+8, l+12
// (arrays R0..R3, R0 = lowest). Unpivoted LU, zero LDS-pipe ops:
//  - pivot broadcasts are STATIC DPP quad_perm (1 inst) — round unrolled 4x,
//    outer round loop rolled (small I$ body)
//  - column-shift trick keeps pivot col at [0] (all reg indices static)
//  - rotation folded into each round's 4th step
// Fallback (tau = 1e-4 * mat_max, ~0.2%/det): rebuild, premultiply by
// M = I + 0.5*C16 (one quad_perm per element, det(M) = 1 - 2^-16 exactly),
// redo unpivoted LU, rescale. Also zero DS ops -> no straggler waves.

template <int CTRL>
__device__ __forceinline__ float dpp_movf(float v) {
    return __int_as_float(__builtin_amdgcn_update_dpp(
        0, __float_as_int(v), CTRL, 0xF, 0xF, true));
}

// Unpivoted LU over a quad. Rows l,l+4,l+8,l+12 in R0..R3. det of product of
// pivots; bad = any pivot below tau (NaN-safe).
__device__ __forceinline__ void lu4(float R0[16], float R1[16], float R2[16],
                                    float R3[16], int l, double& det, bool& bad,
                                    float tau)
{
    det = 1.0;
    bad = false;
    #pragma unroll 1
    for (int g = 0; g < 4; ++g) {
        const bool a1v = (g <= 2), a2v = (g <= 1), a3v = (g == 0);

#define LU_STEP(KK) do {                                                     \
        const float pivot = dpp_movf<(KK) * 0x55>(R0[0]);                    \
        bad = bad || !(fabsf(pivot) >= tau);                                 \
        det *= (double)pivot;                                                \
        float pinv = __builtin_amdgcn_rcpf(pivot);                           \
        pinv = pinv * (2.0f - pivot * pinv);                                 \
        const float f0 = (l > (KK)) ? R0[0] * pinv : 0.0f;                   \
        const float f1 = a1v ? R1[0] * pinv : 0.0f;                          \
        const float f2 = a2v ? R2[0] * pinv : 0.0f;                          \
        const float f3 = a3v ? R3[0] * pinv : 0.0f;                          \
        _Pragma("unroll")                                                    \
        for (int j = 1; j < 16; ++j) {                                       \
            const float pv = dpp_movf<(KK) * 0x55>(R0[j]);                   \
            R0[j - 1] = fmaf(-f0, pv, R0[j]);                                \
            R1[j - 1] = fmaf(-f1, pv, R1[j]);                                \
            R2[j - 1] = fmaf(-f2, pv, R2[j]);                                \
            R3[j - 1] = fmaf(-f3, pv, R3[j]);                                \
        } } while (0)

        LU_STEP(0);
        LU_STEP(1);
        LU_STEP(2);
        {   // step kk==3: R0 retires; rotate R1->R0, R2->R1, R3->R2
            const float pivot = dpp_movf<3 * 0x55>(R0[0]);
            bad = bad || !(fabsf(pivot) >= tau);
            det *= (double)pivot;
            float pinv = __builtin_amdgcn_rcpf(pivot);
            pinv = pinv * (2.0f - pivot * pinv);
            const float f1 = a1v ? R1[0] * pinv : 0.0f;
            const float f2 = a2v ? R2[0] * pinv : 0.0f;
            const float f3 = a3v ? R3[0] * pinv : 0.0f;
            #pragma unroll
            for (int j = 1; j < 16; ++j) {
                const float pv = dpp_movf<3 * 0x55>(R0[j]);
                const float n0 = fmaf(-f1, pv, R1[j]);
                const float n1 = fmaf(-f2, pv, R2[j]);
                const float n2 = fmaf(-f3, pv, R3[j]);
                R0[j - 1] = n0; R1[j - 1] = n1; R2[j - 1] = n2;
            }
        }
#undef LU_STEP
    }
}

// rows_new[i] = rows[i] + 0.5 * rows[(i+1) % 16]  (M = I + 0.5*C16)
// Receiver lane l pulls from lane (l+1)&3 via quad_perm[1,2,3,0] = 0x39;
// sender lane 0 presents its next-slot row (row 4s+4 lives at lane0 slot s+1).
__device__ __forceinline__ void mixrows(float R0[16], float R1[16],
                                        float R2[16], float R3[16], int l)
{
    const bool z = (l == 0);
    #pragma unroll
    for (int j = 0; j < 16; ++j) {
        const float w0 = z ? R1[j] : R0[j];
        const float w1 = z ? R2[j] : R1[j];
        const float w2 = z ? R3[j] : R2[j];
        const float w3 = z ? R0[j] : R3[j];
        R0[j] = fmaf(0.5f, dpp_movf<0x39>(w0), R0[j]);
        R1[j] = fmaf(0.5f, dpp_movf<0x39>(w1), R1[j]);
        R2[j] = fmaf(0.5f, dpp_movf<0x39>(w2), R2[j]);
        R3[j] = fmaf(0.5f, dpp_movf<0x39>(w3), R3[j]);
    }
}

__global__ __launch_bounds__(256, 4) void backflow_kernel(
    const float* __restrict__ x,    // (B,64)
    const float* __restrict__ W1,   // (64,4)
    const float* __restrict__ b1,   // (4,)
    const float* __restrict__ W2,   // (4,4)
    const float* __restrict__ b2,   // (4,)
    const float* __restrict__ Wg,   // (4,16,64,16)
    const float* __restrict__ bg,   // (16,64,16)
    const float* __restrict__ bf,   // (16,1)
    float* __restrict__ out,        // (B,)
    int B)
{
    const int lane  = threadIdx.x & 63;
    const int wavei = threadIdx.x >> 6;
    const int b     = blockIdx.x * 4 + wavei;
    if (b >= B) return;
    const int d = lane >> 2;   // det index 0..15
    const int l = lane & 3;    // lane-in-quad

    // ---- occupied-orbital mask ----
    const float xv = x[b * 64 + lane];
    const unsigned long long mask = __ballot(xv != 0.0f);
    const bool empty = ((mask & ~1ull) == 0ull);

    // ---- h1 = relu(x @ W1 + b1): 64-lane butterfly ----
    const float4 w1 = reinterpret_cast<const float4*>(W1)[lane];
    float c0 = xv * w1.x, c1 = xv * w1.y, c2 = xv * w1.z, c3 = xv * w1.w;
    #pragma unroll
    for (int off = 32; off >= 1; off >>= 1) {
        c0 += __shfl_xor(c0, off);
        c1 += __shfl_xor(c1, off);
        c2 += __shfl_xor(c2, off);
        c3 += __shfl_xor(c3, off);
    }
    const float h10 = fmaxf(c0 + b1[0], 0.0f);
    const float h11 = fmaxf(c1 + b1[1], 0.0f);
    const float h12 = fmaxf(c2 + b1[2], 0.0f);
    const float h13 = fmaxf(c3 + b1[3], 0.0f);

    // ---- h2 = relu(h1 @ W2 + b2) ----
    float h2[4];
    #pragma unroll
    for (int j = 0; j < 4; ++j) {
        float v = b2[j];
        v = fmaf(h10, W2[0 * 4 + j], v);
        v = fmaf(h11, W2[1 * 4 + j], v);
        v = fmaf(h12, W2[2 * 4 + j], v);
        v = fmaf(h13, W2[3 * 4 + j], v);
        h2[j] = fmaxf(v, 0.0f);
    }

    // ---- sel for owned rows l, l+4, l+8, l+12 ----
    unsigned long long m = mask;
    if (l & 1) { m &= m - 1; }
    if (l & 2) { m &= m - 1; m &= m - 1; }
    const int s0 = m ? (int)__builtin_ctzll(m) : 0;
    m &= m - 1; m &= m - 1; m &= m - 1; m &= m - 1;
    const int s1 = m ? (int)__builtin_ctzll(m) : 0;
    m &= m - 1; m &= m - 1; m &= m - 1; m &= m - 1;
    const int s2 = m ? (int)__builtin_ctzll(m) : 0;
    m &= m - 1; m &= m - 1; m &= m - 1; m &= m - 1;
    const int s3 = m ? (int)__builtin_ctzll(m) : 0;

    float R0[16], R1[16], R2[16], R3[16];

#define BUILD_ROW(RW, SQ) do {                                                   \
    const float* base = Wg + ((size_t)d * 64 + (SQ)) * 16;                       \
    const float4* p0 = reinterpret_cast<const float4*>(base);                    \
    const float4* p1 = reinterpret_cast<const float4*>(base + 16384);            \
    const float4* p2 = reinterpret_cast<const float4*>(base + 32768);            \
    const float4* p3 = reinterpret_cast<const float4*>(base + 49152);            \
    const float4* pb = reinterpret_cast<const float4*>(bg + ((size_t)d * 64 + (SQ)) * 16); \
    _Pragma("unroll")                                                            \
    for (int q = 0; q < 4; ++q) {                                                \
        const float4 a0 = p0[q], a1 = p1[q], a2 = p2[q], a3 = p3[q], ab = pb[q]; \
        RW[q*4+0] = fmaf(h2[0],a0.x, fmaf(h2[1],a1.x, fmaf(h2[2],a2.x, fmaf(h2[3],a3.x, ab.x)))); \
        RW[q*4+1] = fmaf(h2[0],a0.y, fmaf(h2[1],a1.y, fmaf(h2[2],a2.y, fmaf(h2[3],a3.y, ab.y)))); \
        RW[q*4+2] = fmaf(h2[0],a0.z, fmaf(h2[1],a1.z, fmaf(h2[2],a2.z, fmaf(h2[3],a3.z, ab.z)))); \
        RW[q*4+3] = fmaf(h2[0],a0.w, fmaf(h2[1],a1.w, fmaf(h2[2],a2.w, fmaf(h2[3],a3.w, ab.w)))); \
    } } while (0)

    BUILD_ROW(R0, s0);
    BUILD_ROW(R1, s1);
    BUILD_ROW(R2, s2);
    BUILD_ROW(R3, s3);

    // ---- matrix scale for pivot-quality flag (quad-uniform) ----
    float mm = 0.0f;
    #pragma unroll
    for (int j = 0; j < 16; ++j) {
        mm = fmaxf(mm, fmaxf(fmaxf(fabsf(R0[j]), fabsf(R1[j])),
                             fmaxf(fabsf(R2[j]), fabsf(R3[j]))));
    }
    mm = fmaxf(mm, dpp_movf<0xB1>(mm));   // quad_perm[1,0,3,2]
    mm = fmaxf(mm, dpp_movf<0x4E>(mm));   // quad_perm[2,3,0,1]
    const float tau = 1e-4f * mm;

    double det;
    bool   bad;
    lu4(R0, R1, R2, R3, l, det, bad, tau);

    // ---- rare zero-DS retry: LU of (I + 0.5*C16) * G, rescale by det(M) ----
    if (bad) {   // bad is quad-uniform
        BUILD_ROW(R0, s0);
        BUILD_ROW(R1, s1);
        BUILD_ROW(R2, s2);
        BUILD_ROW(R3, s3);
        mixrows(R0, R1, R2, R3, l);
        double det2;
        bool   bad2;
        lu4(R0, R1, R2, R3, l, det2, bad2, tau);
        det = det2 * (65536.0 / 65535.0);   // / det(I + 0.5*C16) = 1 - 2^-16
    }
#undef BUILD_ROW

    // ---- combine: det_d (uniform in quad) dotted with bf ----
    const float detf = (float)det;
    float acc = (l == 0) ? detf * bf[d] : 0.0f;
    acc += __shfl_xor(acc, 4);
    acc += __shfl_xor(acc, 8);
    acc += __shfl_xor(acc, 16);
    acc += __shfl_xor(acc, 32);
    if (lane == 0) out[b] = empty ? 0.0f : acc;
}

extern "C" void kernel_launch(void* const* d_in, const int* in_sizes, int n_in,
                              void* d_out, int out_size, void* d_ws, size_t ws_size,
                              hipStream_t stream) {
    const float* x  = (const float*)d_in[0];
    const float* W1 = (const float*)d_in[1];
    const float* b1 = (const float*)d_in[2];
    const float* W2 = (const float*)d_in[3];
    const float* b2 = (const float*)d_in[4];
    const float* Wg = (const float*)d_in[5];
    const float* bg = (const float*)d_in[6];
    const float* bf = (const float*)d_in[7];
    float* out = (float*)d_out;

    const int B = in_sizes[0] / 64;
    const int blocks = (B + 3) / 4;   // 4 samples (waves) per 256-thread block
    backflow_kernel<<<blocks, 256, 0, stream>>>(x, W1, b1, W2, b2, Wg, bg, bf, out, B);
}

// Round 8
// 96.181 us; speedup vs baseline: 1.8349x; 1.8349x over previous
//
#include <hip/hip_runtime.h>

// Backflow: out[b] = sum_d det(g[b,d]) * bf[d]
//   g[b,d][i][j] = sum_h h2[b,h]*Wg[h,d,sel[b,i],j] + bg[d,sel[b,i],j]
// B=8192, O=64, E=16, D=16, H=4.
//
// One wave per sample; 4 lanes per det; lane l owns rows l, l+4, l+8, l+12
// (arrays R0..R3). Unpivoted LU with ZERO LDS-pipe ops in the hot path:
//  - pivot broadcasts = static DPP quad_perm (1 inst each)
//  - column-shift trick keeps the pivot column at index [0] (static reg idx)
//  - slot rotation folded into each round's 4th step
// Fallback (tau = 1e-4 * mat_max): rebuild, premultiply by M = I + 0.5*C16
// (det(M) = 1 - 2^-16 exactly), unpivoted LU again, rescale. Also zero-DS ->
// flagged waves cost ~1.8x fast path, no straggler waves.
// R6 lesson: no min-waves launch_bounds (VGPR cap -> scratch spill).
// R7 lesson: LU4 macro locals must not shadow the caller's DET/BAD args
// (`(DET)=det` bound to the macro's own `det` -> caller got garbage).

template <int CTRL>
__device__ __forceinline__ float dpp_movf(float v) {
    return __int_as_float(__builtin_amdgcn_update_dpp(
        0, __float_as_int(v), CTRL, 0xF, 0xF, true));
}

__global__ __launch_bounds__(256) void backflow_kernel(
    const float* __restrict__ x,    // (B,64)
    const float* __restrict__ W1,   // (64,4)
    const float* __restrict__ b1,   // (4,)
    const float* __restrict__ W2,   // (4,4)
    const float* __restrict__ b2,   // (4,)
    const float* __restrict__ Wg,   // (4,16,64,16)
    const float* __restrict__ bg,   // (16,64,16)
    const float* __restrict__ bf,   // (16,1)
    float* __restrict__ out,        // (B,)
    int B)
{
    const int lane  = threadIdx.x & 63;
    const int wavei = threadIdx.x >> 6;
    const int b     = blockIdx.x * 4 + wavei;
    if (b >= B) return;
    const int d = lane >> 2;   // det index 0..15
    const int l = lane & 3;    // lane-in-quad

    // ---- occupied-orbital mask ----
    const float xv = x[b * 64 + lane];
    const unsigned long long mask = __ballot(xv != 0.0f);
    const bool empty = ((mask & ~1ull) == 0ull);

    // ---- h1 = relu(x @ W1 + b1): 64-lane butterfly ----
    const float4 w1 = reinterpret_cast<const float4*>(W1)[lane];
    float c0 = xv * w1.x, c1 = xv * w1.y, c2 = xv * w1.z, c3 = xv * w1.w;
    #pragma unroll
    for (int off = 32; off >= 1; off >>= 1) {
        c0 += __shfl_xor(c0, off);
        c1 += __shfl_xor(c1, off);
        c2 += __shfl_xor(c2, off);
        c3 += __shfl_xor(c3, off);
    }
    const float h10 = fmaxf(c0 + b1[0], 0.0f);
    const float h11 = fmaxf(c1 + b1[1], 0.0f);
    const float h12 = fmaxf(c2 + b1[2], 0.0f);
    const float h13 = fmaxf(c3 + b1[3], 0.0f);

    // ---- h2 = relu(h1 @ W2 + b2) ----
    float h2[4];
    #pragma unroll
    for (int j = 0; j < 4; ++j) {
        float v = b2[j];
        v = fmaf(h10, W2[0 * 4 + j], v);
        v = fmaf(h11, W2[1 * 4 + j], v);
        v = fmaf(h12, W2[2 * 4 + j], v);
        v = fmaf(h13, W2[3 * 4 + j], v);
        h2[j] = fmaxf(v, 0.0f);
    }

    // ---- sel for owned rows l, l+4, l+8, l+12 ----
    unsigned long long m = mask;
    if (l & 1) { m &= m - 1; }
    if (l & 2) { m &= m - 1; m &= m - 1; }
    const int s0 = m ? (int)__builtin_ctzll(m) : 0;
    m &= m - 1; m &= m - 1; m &= m - 1; m &= m - 1;
    const int s1 = m ? (int)__builtin_ctzll(m) : 0;
    m &= m - 1; m &= m - 1; m &= m - 1; m &= m - 1;
    const int s2 = m ? (int)__builtin_ctzll(m) : 0;
    m &= m - 1; m &= m - 1; m &= m - 1; m &= m - 1;
    const int s3 = m ? (int)__builtin_ctzll(m) : 0;

    float R0[16], R1[16], R2[16], R3[16];

#define BUILD_ROW(RW, SQ) do {                                                   \
    const float* base = Wg + ((size_t)d * 64 + (SQ)) * 16;                       \
    const float4* p0 = reinterpret_cast<const float4*>(base);                    \
    const float4* p1 = reinterpret_cast<const float4*>(base + 16384);            \
    const float4* p2 = reinterpret_cast<const float4*>(base + 32768);            \
    const float4* p3 = reinterpret_cast<const float4*>(base + 49152);            \
    const float4* pb = reinterpret_cast<const float4*>(bg + ((size_t)d * 64 + (SQ)) * 16); \
    _Pragma("unroll")                                                            \
    for (int q = 0; q < 4; ++q) {                                                \
        const float4 a0 = p0[q], a1 = p1[q], a2 = p2[q], a3 = p3[q], ab = pb[q]; \
        RW[q*4+0] = fmaf(h2[0],a0.x, fmaf(h2[1],a1.x, fmaf(h2[2],a2.x, fmaf(h2[3],a3.x, ab.x)))); \
        RW[q*4+1] = fmaf(h2[0],a0.y, fmaf(h2[1],a1.y, fmaf(h2[2],a2.y, fmaf(h2[3],a3.y, ab.y)))); \
        RW[q*4+2] = fmaf(h2[0],a0.z, fmaf(h2[1],a1.z, fmaf(h2[2],a2.z, fmaf(h2[3],a3.z, ab.z)))); \
        RW[q*4+3] = fmaf(h2[0],a0.w, fmaf(h2[1],a1.w, fmaf(h2[2],a2.w, fmaf(h2[3],a3.w, ab.w)))); \
    } } while (0)

    BUILD_ROW(R0, s0);
    BUILD_ROW(R1, s1);
    BUILD_ROW(R2, s2);
    BUILD_ROW(R3, s3);

    // ---- matrix scale for pivot-quality flag (quad-uniform) ----
    float mm = 0.0f;
    #pragma unroll
    for (int j = 0; j < 16; ++j) {
        mm = fmaxf(mm, fmaxf(fmaxf(fabsf(R0[j]), fabsf(R1[j])),
                             fmaxf(fabsf(R2[j]), fabsf(R3[j]))));
    }
    mm = fmaxf(mm, dpp_movf<0xB1>(mm));   // quad_perm[1,0,3,2]
    mm = fmaxf(mm, dpp_movf<0x4E>(mm));   // quad_perm[2,3,0,1]
    const float tau = 1e-4f * mm;

    // ---- unpivoted LU, zero-DS; rounds of 4 steps; rotation in step 4 ----
    // NOTE hygienic locals _lu_det/_lu_bad so (DET)/(BAD) bind to the caller.
#define LU_STEP(KK, A1V, A2V, A3V) do {                                      \
        const float pivot = dpp_movf<(KK) * 0x55>(R0[0]);                    \
        _lu_bad = _lu_bad || !(fabsf(pivot) >= tau);                         \
        _lu_det *= (double)pivot;                                            \
        float pinv = __builtin_amdgcn_rcpf(pivot);                           \
        pinv = pinv * (2.0f - pivot * pinv);                                 \
        const float f0 = (l > (KK)) ? R0[0] * pinv : 0.0f;                   \
        const float f1 = (A1V) ? R1[0] * pinv : 0.0f;                        \
        const float f2 = (A2V) ? R2[0] * pinv : 0.0f;                        \
        const float f3 = (A3V) ? R3[0] * pinv : 0.0f;                        \
        _Pragma("unroll")                                                    \
        for (int j = 1; j < 16; ++j) {                                       \
            const float pv = dpp_movf<(KK) * 0x55>(R0[j]);                   \
            R0[j - 1] = fmaf(-f0, pv, R0[j]);                                \
            R1[j - 1] = fmaf(-f1, pv, R1[j]);                                \
            R2[j - 1] = fmaf(-f2, pv, R2[j]);                                \
            R3[j - 1] = fmaf(-f3, pv, R3[j]);                                \
        } } while (0)

#define LU_STEP3_ROT(A1V, A2V, A3V) do {                                     \
        const float pivot = dpp_movf<3 * 0x55>(R0[0]);                       \
        _lu_bad = _lu_bad || !(fabsf(pivot) >= tau);                         \
        _lu_det *= (double)pivot;                                            \
        float pinv = __builtin_amdgcn_rcpf(pivot);                           \
        pinv = pinv * (2.0f - pivot * pinv);                                 \
        const float f1 = (A1V) ? R1[0] * pinv : 0.0f;                        \
        const float f2 = (A2V) ? R2[0] * pinv : 0.0f;                        \
        const float f3 = (A3V) ? R3[0] * pinv : 0.0f;                        \
        _Pragma("unroll")                                                    \
        for (int j = 1; j < 16; ++j) {                                       \
            const float pv = dpp_movf<3 * 0x55>(R0[j]);                      \
            const float n0 = fmaf(-f1, pv, R1[j]);                           \
            const float n1 = fmaf(-f2, pv, R2[j]);                           \
            const float n2 = fmaf(-f3, pv, R3[j]);                           \
            R0[j - 1] = n0; R1[j - 1] = n1; R2[j - 1] = n2;                  \
        } } while (0)

#define LU4(DET, BAD) do {                                                   \
        double _lu_det = 1.0; bool _lu_bad = false;                          \
        _Pragma("unroll 1")                                                  \
        for (int g = 0; g < 4; ++g) {                                        \
            const bool a1v = (g <= 2), a2v = (g <= 1), a3v = (g == 0);       \
            LU_STEP(0, a1v, a2v, a3v);                                       \
            LU_STEP(1, a1v, a2v, a3v);                                       \
            LU_STEP(2, a1v, a2v, a3v);                                       \
            LU_STEP3_ROT(a1v, a2v, a3v);                                     \
        }                                                                    \
        (DET) = _lu_det; (BAD) = _lu_bad; } while (0)

    double det;
    bool   bad;
    LU4(det, bad);

    // ---- rare zero-DS retry: LU of (I + 0.5*C16)*G, rescale by det(M) ----
    if (bad) {   // bad is quad-uniform
        BUILD_ROW(R0, s0);
        BUILD_ROW(R1, s1);
        BUILD_ROW(R2, s2);
        BUILD_ROW(R3, s3);
        // rows_new[i] = rows[i] + 0.5*rows[(i+1)%16]; receiver pulls from
        // lane (l+1)&3 (quad_perm[1,2,3,0]=0x39); lane 0 presents slot+1.
        {
            const bool z = (l == 0);
            #pragma unroll
            for (int j = 0; j < 16; ++j) {
                const float w0 = z ? R1[j] : R0[j];
                const float w1 = z ? R2[j] : R1[j];
                const float w2 = z ? R3[j] : R2[j];
                const float w3 = z ? R0[j] : R3[j];
                R0[j] = fmaf(0.5f, dpp_movf<0x39>(w0), R0[j]);
                R1[j] = fmaf(0.5f, dpp_movf<0x39>(w1), R1[j]);
                R2[j] = fmaf(0.5f, dpp_movf<0x39>(w2), R2[j]);
                R3[j] = fmaf(0.5f, dpp_movf<0x39>(w3), R3[j]);
            }
        }
        double det2;
        bool   bad2;
        LU4(det2, bad2);
        (void)bad2;
        det = det2 * (65536.0 / 65535.0);   // / det(I + 0.5*C16)
    }
#undef LU4
#undef LU_STEP3_ROT
#undef LU_STEP
#undef BUILD_ROW

    // ---- combine: det_d (uniform in quad) dotted with bf ----
    const float detf = (float)det;
    float acc = (l == 0) ? detf * bf[d] : 0.0f;
    acc += __shfl_xor(acc, 4);
    acc += __shfl_xor(acc, 8);
    acc += __shfl_xor(acc, 16);
    acc += __shfl_xor(acc, 32);
    if (lane == 0) out[b] = empty ? 0.0f : acc;
}

extern "C" void kernel_launch(void* const* d_in, const int* in_sizes, int n_in,
                              void* d_out, int out_size, void* d_ws, size_t ws_size,
                              hipStream_t stream) {
    const float* x  = (const float*)d_in[0];
    const float* W1 = (const float*)d_in[1];
    const float* b1 = (const float*)d_in[2];
    const float* W2 = (const float*)d_in[3];
    const float* b2 = (const float*)d_in[4];
    const float* Wg = (const float*)d_in[5];
    const float* bg = (const float*)d_in[6];
    const float* bf = (const float*)d_in[7];
    float* out = (float*)d_out;

    const int B = in_sizes[0] / 64;
    const int blocks = (B + 3) / 4;   // 4 samples (waves) per 256-thread block
    backflow_kernel<<<blocks, 256, 0, stream>>>(x, W1, b1, W2, b2, Wg, bg, bf, out, B);
}

// Round 9
// 76.648 us; speedup vs baseline: 2.3024x; 1.2548x over previous
//
#include <hip/hip_runtime.h>

// Backflow: out[b] = sum_d det(g[b,d]) * bf[d]
//   g[b,d][i][j] = sum_h h2[b,h]*Wg[h,d,sel[b,i],j] + bg[d,sel[b,i],j]
// B=8192, O=64, E=16, D=16, H=4.
//
// One wave per sample; 4 lanes per det; lane l owns physical rows l, l+4,
// l+8, l+12 (arrays R0..R3). FULLY-UNROLLED unpivoted LU, zero LDS-pipe ops:
//  - pivot broadcasts = static DPP quad_perm (1 inst each)
//  - column-shift keeps pivot col at [0]; j-extent shrinks with k (j<=15-k)
//  - retired arrays statically dropped per round (4/3/2/1 updates)
// Retry (tau = 1e-4 * mat_max): attempt-loop rebuilds, premultiplies by
// M = I + 0.5*C16 (det exactly 1 - 2^-16), re-runs the same LU text.
// R6 lesson: no min-waves launch_bounds (VGPR cap -> scratch spill).
// R7 lesson: macro locals must not shadow caller outputs.
// R8 lesson: VGPR 164 -> 3 waves/SIMD; build load-pipeline is the pressure.

template <int CTRL>
__device__ __forceinline__ float dpp_movf(float v) {
    return __int_as_float(__builtin_amdgcn_update_dpp(
        0, __float_as_int(v), CTRL, 0xF, 0xF, true));
}

__global__ __launch_bounds__(256) void backflow_kernel(
    const float* __restrict__ x,    // (B,64)
    const float* __restrict__ W1,   // (64,4)
    const float* __restrict__ b1,   // (4,)
    const float* __restrict__ W2,   // (4,4)
    const float* __restrict__ b2,   // (4,)
    const float* __restrict__ Wg,   // (4,16,64,16)
    const float* __restrict__ bg,   // (16,64,16)
    const float* __restrict__ bf,   // (16,1)
    float* __restrict__ out,        // (B,)
    int B)
{
    const int lane  = threadIdx.x & 63;
    const int wavei = threadIdx.x >> 6;
    const int b     = blockIdx.x * 4 + wavei;
    if (b >= B) return;
    const int d = lane >> 2;   // det index 0..15
    const int l = lane & 3;    // lane-in-quad

    // ---- occupied-orbital mask ----
    const float xv = x[b * 64 + lane];
    const unsigned long long mask = __ballot(xv != 0.0f);
    const bool empty = ((mask & ~1ull) == 0ull);

    // ---- h1 = relu(x @ W1 + b1): 64-lane butterfly ----
    const float4 w1 = reinterpret_cast<const float4*>(W1)[lane];
    float c0 = xv * w1.x, c1 = xv * w1.y, c2 = xv * w1.z, c3 = xv * w1.w;
    #pragma unroll
    for (int off = 32; off >= 1; off >>= 1) {
        c0 += __shfl_xor(c0, off);
        c1 += __shfl_xor(c1, off);
        c2 += __shfl_xor(c2, off);
        c3 += __shfl_xor(c3, off);
    }
    const float h10 = fmaxf(c0 + b1[0], 0.0f);
    const float h11 = fmaxf(c1 + b1[1], 0.0f);
    const float h12 = fmaxf(c2 + b1[2], 0.0f);
    const float h13 = fmaxf(c3 + b1[3], 0.0f);

    // ---- h2 = relu(h1 @ W2 + b2) ----
    float h2[4];
    #pragma unroll
    for (int j = 0; j < 4; ++j) {
        float v = b2[j];
        v = fmaf(h10, W2[0 * 4 + j], v);
        v = fmaf(h11, W2[1 * 4 + j], v);
        v = fmaf(h12, W2[2 * 4 + j], v);
        v = fmaf(h13, W2[3 * 4 + j], v);
        h2[j] = fmaxf(v, 0.0f);
    }

    // ---- sel for owned rows l, l+4, l+8, l+12 ----
    unsigned long long m = mask;
    if (l & 1) { m &= m - 1; }
    if (l & 2) { m &= m - 1; m &= m - 1; }
    const int s0 = m ? (int)__builtin_ctzll(m) : 0;
    m &= m - 1; m &= m - 1; m &= m - 1; m &= m - 1;
    const int s1 = m ? (int)__builtin_ctzll(m) : 0;
    m &= m - 1; m &= m - 1; m &= m - 1; m &= m - 1;
    const int s2 = m ? (int)__builtin_ctzll(m) : 0;
    m &= m - 1; m &= m - 1; m &= m - 1; m &= m - 1;
    const int s3 = m ? (int)__builtin_ctzll(m) : 0;

    float R0[16], R1[16], R2[16], R3[16];

#define BUILD_ROW(RW, SQ) do {                                                   \
    const float* base = Wg + ((size_t)d * 64 + (SQ)) * 16;                       \
    const float4* p0 = reinterpret_cast<const float4*>(base);                    \
    const float4* p1 = reinterpret_cast<const float4*>(base + 16384);            \
    const float4* p2 = reinterpret_cast<const float4*>(base + 32768);            \
    const float4* p3 = reinterpret_cast<const float4*>(base + 49152);            \
    const float4* pb = reinterpret_cast<const float4*>(bg + ((size_t)d * 64 + (SQ)) * 16); \
    _Pragma("unroll 2")                                                          \
    for (int q = 0; q < 4; ++q) {                                                \
        const float4 a0 = p0[q], a1 = p1[q], a2 = p2[q], a3 = p3[q], ab = pb[q]; \
        RW[q*4+0] = fmaf(h2[0],a0.x, fmaf(h2[1],a1.x, fmaf(h2[2],a2.x, fmaf(h2[3],a3.x, ab.x)))); \
        RW[q*4+1] = fmaf(h2[0],a0.y, fmaf(h2[1],a1.y, fmaf(h2[2],a2.y, fmaf(h2[3],a3.y, ab.y)))); \
        RW[q*4+2] = fmaf(h2[0],a0.z, fmaf(h2[1],a1.z, fmaf(h2[2],a2.z, fmaf(h2[3],a3.z, ab.z)))); \
        RW[q*4+3] = fmaf(h2[0],a0.w, fmaf(h2[1],a1.w, fmaf(h2[2],a2.w, fmaf(h2[3],a3.w, ab.w)))); \
    } } while (0)

#define BUILD4 do {                                                          \
        BUILD_ROW(R0, s0); __builtin_amdgcn_sched_barrier(0);                \
        BUILD_ROW(R1, s1); __builtin_amdgcn_sched_barrier(0);                \
        BUILD_ROW(R2, s2); __builtin_amdgcn_sched_barrier(0);                \
        BUILD_ROW(R3, s3); __builtin_amdgcn_sched_barrier(0);                \
    } while (0)

    // ---- triangular unpivoted LU steps (K static everywhere) ----
    // Pivot row K lives at lane K&3, array K>>2, shifted col [0].
    // nb counts below-tau pivots (NaN-safe); det split over 2 f64 chains.
#define STEP4(K, DAC, PA, PB, PC, PD) do {                                   \
        const float pivot = dpp_movf<((K) & 3) * 0x55>(PA[0]);               \
        nb += !(fabsf(pivot) >= tau);                                        \
        DAC *= (double)pivot;                                                \
        const float pinv = __builtin_amdgcn_rcpf(pivot);                     \
        const float fa = (l > ((K) & 3)) ? PA[0] * pinv : 0.0f;              \
        const float fb = PB[0] * pinv;                                       \
        const float fc = PC[0] * pinv;                                       \
        const float fd = PD[0] * pinv;                                       \
        _Pragma("unroll")                                                    \
        for (int j = 1; j <= 15 - (K); ++j) {                                \
            const float pv = dpp_movf<((K) & 3) * 0x55>(PA[j]);              \
            PA[j - 1] = fmaf(-fa, pv, PA[j]);                                \
            PB[j - 1] = fmaf(-fb, pv, PB[j]);                                \
            PC[j - 1] = fmaf(-fc, pv, PC[j]);                                \
            PD[j - 1] = fmaf(-fd, pv, PD[j]);                                \
        } } while (0)

#define STEP3(K, DAC, PA, PB, PC) do {                                       \
        const float pivot = dpp_movf<((K) & 3) * 0x55>(PA[0]);               \
        nb += !(fabsf(pivot) >= tau);                                        \
        DAC *= (double)pivot;                                                \
        const float pinv = __builtin_amdgcn_rcpf(pivot);                     \
        const float fa = (l > ((K) & 3)) ? PA[0] * pinv : 0.0f;              \
        const float fb = PB[0] * pinv;                                       \
        const float fc = PC[0] * pinv;                                       \
        _Pragma("unroll")                                                    \
        for (int j = 1; j <= 15 - (K); ++j) {                                \
            const float pv = dpp_movf<((K) & 3) * 0x55>(PA[j]);              \
            PA[j - 1] = fmaf(-fa, pv, PA[j]);                                \
            PB[j - 1] = fmaf(-fb, pv, PB[j]);                                \
            PC[j - 1] = fmaf(-fc, pv, PC[j]);                                \
        } } while (0)

#define STEP2(K, DAC, PA, PB) do {                                           \
        const float pivot = dpp_movf<((K) & 3) * 0x55>(PA[0]);               \
        nb += !(fabsf(pivot) >= tau);                                        \
        DAC *= (double)pivot;                                                \
        const float pinv = __builtin_amdgcn_rcpf(pivot);                     \
        const float fa = (l > ((K) & 3)) ? PA[0] * pinv : 0.0f;              \
        const float fb = PB[0] * pinv;                                       \
        _Pragma("unroll")                                                    \
        for (int j = 1; j <= 15 - (K); ++j) {                                \
            const float pv = dpp_movf<((K) & 3) * 0x55>(PA[j]);              \
            PA[j - 1] = fmaf(-fa, pv, PA[j]);                                \
            PB[j - 1] = fmaf(-fb, pv, PB[j]);                                \
        } } while (0)

#define STEP1(K, DAC, PA) do {                                               \
        const float pivot = dpp_movf<((K) & 3) * 0x55>(PA[0]);               \
        nb += !(fabsf(pivot) >= tau);                                        \
        DAC *= (double)pivot;                                                \
        const float pinv = __builtin_amdgcn_rcpf(pivot);                     \
        const float fa = (l > ((K) & 3)) ? PA[0] * pinv : 0.0f;              \
        _Pragma("unroll")                                                    \
        for (int j = 1; j <= 15 - (K); ++j) {                                \
            const float pv = dpp_movf<((K) & 3) * 0x55>(PA[j]);              \
            PA[j - 1] = fmaf(-fa, pv, PA[j]);                                \
        } } while (0)

    BUILD4;

    // ---- matrix scale for pivot-quality flag (quad-uniform) ----
    float mm = 0.0f;
    #pragma unroll
    for (int j = 0; j < 16; ++j) {
        mm = fmaxf(mm, fmaxf(fmaxf(fabsf(R0[j]), fabsf(R1[j])),
                             fmaxf(fabsf(R2[j]), fabsf(R3[j]))));
    }
    mm = fmaxf(mm, dpp_movf<0xB1>(mm));   // quad_perm[1,0,3,2]
    mm = fmaxf(mm, dpp_movf<0x4E>(mm));   // quad_perm[2,3,0,1]
    const float tau = 1e-4f * mm;

    double deta, detb;
    bool   retried = false;

    #pragma unroll 1
    for (int attempt = 0; attempt < 2; ++attempt) {
        if (attempt) {   // rebuild + premultiply by M = I + 0.5*C16
            BUILD4;
            const bool z = (l == 0);
            #pragma unroll
            for (int j = 0; j < 16; ++j) {
                const float w0 = z ? R1[j] : R0[j];
                const float w1 = z ? R2[j] : R1[j];
                const float w2 = z ? R3[j] : R2[j];
                const float w3 = z ? R0[j] : R3[j];
                R0[j] = fmaf(0.5f, dpp_movf<0x39>(w0), R0[j]);
                R1[j] = fmaf(0.5f, dpp_movf<0x39>(w1), R1[j]);
                R2[j] = fmaf(0.5f, dpp_movf<0x39>(w2), R2[j]);
                R3[j] = fmaf(0.5f, dpp_movf<0x39>(w3), R3[j]);
            }
            retried = true;
        }
        deta = 1.0; detb = 1.0;
        int nb = 0;

        STEP4(0,  deta, R0, R1, R2, R3);
        STEP4(1,  detb, R0, R1, R2, R3);
        STEP4(2,  deta, R0, R1, R2, R3);
        STEP4(3,  detb, R0, R1, R2, R3);
        STEP3(4,  deta, R1, R2, R3);
        STEP3(5,  detb, R1, R2, R3);
        STEP3(6,  deta, R1, R2, R3);
        STEP3(7,  detb, R1, R2, R3);
        STEP2(8,  deta, R2, R3);
        STEP2(9,  detb, R2, R3);
        STEP2(10, deta, R2, R3);
        STEP2(11, detb, R2, R3);
        STEP1(12, deta, R3);
        STEP1(13, detb, R3);
        STEP1(14, deta, R3);
        STEP1(15, detb, R3);

        if (nb == 0) break;   // nb is quad-uniform; bad quads loop again
    }
#undef STEP1
#undef STEP2
#undef STEP3
#undef STEP4
#undef BUILD4
#undef BUILD_ROW

    // ---- combine: det_d (uniform in quad) dotted with bf ----
    float detf = (float)(deta * detb);
    if (retried) detf *= (65536.0f / 65535.0f);   // / det(I + 0.5*C16)
    float acc = (l == 0) ? detf * bf[d] : 0.0f;
    acc += __shfl_xor(acc, 4);
    acc += __shfl_xor(acc, 8);
    acc += __shfl_xor(acc, 16);
    acc += __shfl_xor(acc, 32);
    if (lane == 0) out[b] = empty ? 0.0f : acc;
}

extern "C" void kernel_launch(void* const* d_in, const int* in_sizes, int n_in,
                              void* d_out, int out_size, void* d_ws, size_t ws_size,
                              hipStream_t stream) {
    const float* x  = (const float*)d_in[0];
    const float* W1 = (const float*)d_in[1];
    const float* b1 = (const float*)d_in[2];
    const float* W2 = (const float*)d_in[3];
    const float* b2 = (const float*)d_in[4];
    const float* Wg = (const float*)d_in[5];
    const float* bg = (const float*)d_in[6];
    const float* bf = (const float*)d_in[7];
    float* out = (float*)d_out;

    const int B = in_sizes[0] / 64;
    const int blocks = (B + 3) / 4;   // 4 samples (waves) per 256-thread block
    backflow_kernel<<<blocks, 256, 0, stream>>>(x, W1, b1, W2, b2, Wg, bg, bf, out, B);
}